// Round 1
// baseline (5264.325 us; speedup 1.0000x reference)
//
#include <hip/hip_runtime.h>

// AdaptiveDownsampling: farthest point sampling (B=8, N=8192, m=4096) + gather.
// Outputs concatenated flat: dp [8,4096,3] then df [8,4096,256], float32.
//
// r2: np reference computes in float64 -> exact path must be fp64.
// r3-r5: register-array spill / AGPR tax lessons; named scalars only.
// r6: fp32 screen + rare exact fp64 path (sound: nonneg terms, rel err
//     <=1.1e-6 << 1e-4 margin). 5275 us.
// r7: DPP wave max (2x u32 passes), packed-fp32 screen, precomputed margin.
//     4239 us (~2500 cyc/iter).
// r8: single-barrier iteration. Each wave publishes (max_hi, max_lo,
//     min_idx_at_max) to its OWN LDS slot (no atomics, no same-address
//     funnel); after ONE barrier every wave redundantly block-reduces the
//     16 entries with the same DPP ladder (lanes read entry lane&15 ->
//     broadcast, conflict-free; duplicated rows are max-idempotent).
//     Index tie-break stays exact: global idx = slot*1024+tid, so block min
//     = min over per-wave mins. Table double-buffered by k&1: a wave must
//     consume its reads (lgkm wait) before reaching the next barrier, which
//     gates the next overwrite of that parity -> race-free with 1 barrier.

typedef float v2f __attribute__((ext_vector_type(2)));

#define BATCH 8
#define NPTS  8192
#define MSEL  4096
#define NFEAT 256
#define BLOCK 1024
#define NWAVE (BLOCK / 64)

// fp64 square, opaque to the compiler so no v_fma_f64 contraction can merge
// the following adds (numpy float64 does separate mul / add / add).
__device__ __forceinline__ double sqd(double x) {
    double r;
    asm("v_mul_f64 %0, %1, %1" : "=v"(r) : "v"(x));
    return r;
}

// Exact 64-lane u32 max, VALU-only (DPP), result broadcast via lane 63.
// Canonical gfx9 sequence; invalid-source lanes contribute old=0 (safe: all
// inputs nonneg). Uniform control flow required at call site.
__device__ __forceinline__ unsigned wave_umax(unsigned v) {
    unsigned t;
    t = (unsigned)__builtin_amdgcn_update_dpp(0, (int)v, 0x111, 0xf, 0xf, false); v = v > t ? v : t; // row_shr:1
    t = (unsigned)__builtin_amdgcn_update_dpp(0, (int)v, 0x112, 0xf, 0xf, false); v = v > t ? v : t; // row_shr:2
    t = (unsigned)__builtin_amdgcn_update_dpp(0, (int)v, 0x114, 0xf, 0xf, false); v = v > t ? v : t; // row_shr:4
    t = (unsigned)__builtin_amdgcn_update_dpp(0, (int)v, 0x118, 0xf, 0xf, false); v = v > t ? v : t; // row_shr:8
    t = (unsigned)__builtin_amdgcn_update_dpp(0, (int)v, 0x142, 0xf, 0xf, false); v = v > t ? v : t; // row_bcast:15
    t = (unsigned)__builtin_amdgcn_update_dpp(0, (int)v, 0x143, 0xf, 0xf, false); v = v > t ? v : t; // row_bcast:31
    return (unsigned)__builtin_amdgcn_readlane((int)v, 63);
}

// Exact 64-lane u32 min; invalid-source lanes contribute old=0xffffffff.
__device__ __forceinline__ unsigned wave_umin(unsigned v) {
    unsigned t;
    t = (unsigned)__builtin_amdgcn_update_dpp(-1, (int)v, 0x111, 0xf, 0xf, false); v = v < t ? v : t; // row_shr:1
    t = (unsigned)__builtin_amdgcn_update_dpp(-1, (int)v, 0x112, 0xf, 0xf, false); v = v < t ? v : t; // row_shr:2
    t = (unsigned)__builtin_amdgcn_update_dpp(-1, (int)v, 0x114, 0xf, 0xf, false); v = v < t ? v : t; // row_shr:4
    t = (unsigned)__builtin_amdgcn_update_dpp(-1, (int)v, 0x118, 0xf, 0xf, false); v = v < t ? v : t; // row_shr:8
    t = (unsigned)__builtin_amdgcn_update_dpp(-1, (int)v, 0x142, 0xf, 0xf, false); v = v < t ? v : t; // row_bcast:15
    t = (unsigned)__builtin_amdgcn_update_dpp(-1, (int)v, 0x143, 0xf, 0xf, false); v = v < t ? v : t; // row_bcast:31
    return (unsigned)__builtin_amdgcn_readlane((int)v, 63);
}

__launch_bounds__(BLOCK, 1)
__global__ void fps_kernel(const float* __restrict__ pts,   // [B, N, 3]
                           float* __restrict__ dp,          // [B, M, 3]
                           int* __restrict__ idx_out)       // [B, M]
{
    __shared__ float s_pts[NPTS * 3];            // 96 KB fp32 copy (winner broadcast)
    __shared__ unsigned s_rhi[2][NWAVE];         // per-wave max, double bits hi32
    __shared__ unsigned s_rlo[2][NWAVE];         // per-wave max, double bits lo32
    __shared__ unsigned s_rn [2][NWAVE];         // per-wave min index at max

    const int b   = blockIdx.x;
    const int tid = threadIdx.x;
    const int lane = tid & 63;
    const int wid  = tid >> 6;
    const float* p = pts + (size_t)b * NPTS * 3;

    for (int i = tid; i < NPTS * 3; i += BLOCK) s_pts[i] = p[i];

    // Coords as float2 pairs (slots 2P, 2P+1) -> packed-fp32 screen.
    // mind (fp64 exact) + mfm (pre-margined fp32 screen threshold) per slot.
#define DECLP(P, J0, J1) \
    v2f pxp##P = { p[(tid + J0 * 1024) * 3 + 0], p[(tid + J1 * 1024) * 3 + 0] }; \
    v2f pyp##P = { p[(tid + J0 * 1024) * 3 + 1], p[(tid + J1 * 1024) * 3 + 1] }; \
    v2f pzp##P = { p[(tid + J0 * 1024) * 3 + 2], p[(tid + J1 * 1024) * 3 + 2] };
    DECLP(0, 0, 1) DECLP(1, 2, 3) DECLP(2, 4, 5) DECLP(3, 6, 7)
#undef DECLP
    double mind0 = 1e10, mind1 = 1e10, mind2 = 1e10, mind3 = 1e10;
    double mind4 = 1e10, mind5 = 1e10, mind6 = 1e10, mind7 = 1e10;
    float  mfm0 = 1.0001e10f, mfm1 = 1.0001e10f, mfm2 = 1.0001e10f, mfm3 = 1.0001e10f;
    float  mfm4 = 1.0001e10f, mfm5 = 1.0001e10f, mfm6 = 1.0001e10f, mfm7 = 1.0001e10f;

    // Selection 0 is point 0 (deterministic start).
    float cx = p[0], cy = p[1], cz = p[2];
    if (tid == 0) {
        dp[(size_t)b * MSEL * 3 + 0] = cx;
        dp[(size_t)b * MSEL * 3 + 1] = cy;
        dp[(size_t)b * MSEL * 3 + 2] = cz;
        idx_out[b * MSEL + 0] = 0;
    }

    double tbv   = 0.0;     // cached thread-local max of mind0..7
    bool   dirty = true;

    __syncthreads();   // s_pts visible

    for (int k = 1; k < MSEL; ++k) {
        const double cxd = (double)cx, cyd = (double)cy, czd = (double)cz;
        const v2f cx2 = {cx, cx}, cy2 = {cy, cy}, cz2 = {cz, cz};

        // --- packed fp32 screen; exact fp64 update only on trigger ---
#define EX64(PX, PY, PZ, J) { \
        const double ddx = (double)(PX) - cxd; \
        const double ddy = (double)(PY) - cyd; \
        const double ddz = (double)(PZ) - czd; \
        const double dd  = (sqd(ddx) + sqd(ddy)) + sqd(ddz); \
        if (dd < mind##J) { mind##J = dd; mfm##J = (float)dd * 1.0001f; dirty = true; } }
#define UPDP(P, J0, J1) { \
        const v2f dx = pxp##P - cx2, dy = pyp##P - cy2, dz = pzp##P - cz2; \
        const v2f d  = dx * dx + dy * dy + dz * dz; \
        if (d.x < mfm##J0) EX64(pxp##P.x, pyp##P.x, pzp##P.x, J0) \
        if (d.y < mfm##J1) EX64(pxp##P.y, pyp##P.y, pzp##P.y, J1) }
        UPDP(0, 0, 1) UPDP(1, 2, 3) UPDP(2, 4, 5) UPDP(3, 6, 7)
#undef UPDP
#undef EX64

        // --- thread-local max, recomputed only when a slot changed ---
        if (dirty) {
            const double a0 = fmax(mind0, mind1), a1 = fmax(mind2, mind3);
            const double a2 = fmax(mind4, mind5), a3 = fmax(mind6, mind7);
            tbv = fmax(fmax(a0, a1), fmax(a2, a3));
            dirty = false;
        }

        // --- wave max of nonneg double bits: two u32 DPP passes (exact) ---
        const unsigned long long tb = (unsigned long long)__double_as_longlong(tbv);
        const unsigned thi = (unsigned)(tb >> 32);
        const unsigned tlo = (unsigned)tb;
        const unsigned whi = wave_umax(thi);
        const unsigned wlo = wave_umax(thi == whi ? tlo : 0u);

        // --- per-wave min index among this wave's owners (numpy tie-break:
        //     global idx = slot*1024 + tid, scan high slot -> low slot so the
        //     smallest index wins last assignment) ---
        int n = 0x7fffffff;
        if (thi == whi && tlo == wlo) {
            if (mind7 == tbv) n = tid + 7 * 1024;
            if (mind6 == tbv) n = tid + 6 * 1024;
            if (mind5 == tbv) n = tid + 5 * 1024;
            if (mind4 == tbv) n = tid + 4 * 1024;
            if (mind3 == tbv) n = tid + 3 * 1024;
            if (mind2 == tbv) n = tid + 2 * 1024;
            if (mind1 == tbv) n = tid + 1 * 1024;
            if (mind0 == tbv) n = tid;
        }
        const unsigned wn = wave_umin((unsigned)n);

        // --- publish per-wave result to own slot; ONE barrier ---
        const int buf = k & 1;
        if (lane == 0) {
            s_rhi[buf][wid] = whi;
            s_rlo[buf][wid] = wlo;
            s_rn [buf][wid] = wn;
        }
        __syncthreads();

        // --- every wave redundantly reduces the 16 entries (broadcast reads,
        //     rows duplicated 4x: max/min idempotent) ---
        const int e = lane & (NWAVE - 1);
        const unsigned ehi = s_rhi[buf][e];
        const unsigned elo = s_rlo[buf][e];
        const unsigned en  = s_rn [buf][e];
        const unsigned bhi = wave_umax(ehi);
        const unsigned blo = wave_umax(ehi == bhi ? elo : 0u);
        const unsigned bn  = wave_umin((ehi == bhi && elo == blo) ? en : 0xffffffffu);
        const int widx = (int)bn;   // wave-uniform (readlane-broadcast)

        // --- broadcast winner coords from LDS (same-addr = conflict-free) ---
        const float wx = s_pts[widx * 3 + 0];
        const float wy = s_pts[widx * 3 + 1];
        const float wz = s_pts[widx * 3 + 2];
        if (tid == 0) {
            idx_out[b * MSEL + k] = widx;
            float* o = dp + ((size_t)b * MSEL + k) * 3;
            o[0] = wx; o[1] = wy; o[2] = wz;
        }
        cx = wx; cy = wy; cz = wz;
    }
}

// One wave per selected row; lane i moves one float4 (64 * 16B = 1024B = full row).
__global__ void gather_kernel(const float* __restrict__ feats,  // [B, N, C]
                              const int* __restrict__ idx,      // [B, M]
                              float* __restrict__ df)           // [B, M, C]
{
    const int row  = blockIdx.x * 4 + (threadIdx.x >> 6);  // [0, B*M)
    const int lane = threadIdx.x & 63;
    const int b    = row >> 12;         // MSEL = 4096 rows per batch
    const int src  = idx[row];
    const float4* s = (const float4*)(feats + ((size_t)b * NPTS + src) * NFEAT);
    float4*       d = (float4*)(df + (size_t)row * NFEAT);
    d[lane] = s[lane];
}

extern "C" void kernel_launch(void* const* d_in, const int* in_sizes, int n_in,
                              void* d_out, int out_size, void* d_ws, size_t ws_size,
                              hipStream_t stream)
{
    const float* points   = (const float*)d_in[0];   // [8, 8192, 3]
    const float* features = (const float*)d_in[1];   // [8, 8192, 256]
    float* out = (float*)d_out;
    float* dp  = out;                                // [8, 4096, 3]
    float* df  = out + (size_t)BATCH * MSEL * 3;     // [8, 4096, 256]
    int*   idx_ws = (int*)d_ws;                      // [8, 4096] = 128 KB scratch

    fps_kernel<<<BATCH, BLOCK, 0, stream>>>(points, dp, idx_ws);
    gather_kernel<<<(BATCH * MSEL) / 4, 256, 0, stream>>>(features, idx_ws, df);
}

// Round 2
// 4197.639 us; speedup vs baseline: 1.2541x; 1.2541x over previous
//
#include <hip/hip_runtime.h>

// AdaptiveDownsampling: farthest point sampling (B=8, N=8192, m=4096) + gather.
// Outputs concatenated flat: dp [8,4096,3] then df [8,4096,256], float32.
//
// r2: np reference computes in float64 -> exact path must be fp64.
// r3-r5: register-array spill / AGPR tax lessons; named scalars only.
// r6: fp32 screen + rare exact fp64 path (sound: nonneg terms, rel err
//     <=1.1e-6 << 1e-4 margin). 5275 us.
// r7: DPP wave max (2x u32 passes), packed-fp32 screen, precomputed margin.
//     4239 us (~2500 cyc/iter).
// r8: FAILED (5264 us): single-barrier + per-wave LDS slots + redundant
//     block reduce in every wave. Lesson: barriers/atomics were NOT the
//     bottleneck; dependent DPP ladders x16 waves (VALU issue + latency) are.
// r9: dirty-wave caching. mind only decreases => a wave's (max, owner-idx)
//     is unchanged unless one of its lanes updated this iteration (winner's
//     wave always updates: its mind -> 0). Cache (whi, wlo, wn) per wave in
//     SGPRs; recompute only when __any(dirty) (~1-4 of 16 waves per iter).
//     Ladders fused to single v_max_u32_dpp ops (bound_ctrl:0 => invalid
//     lanes read 0, identity for unsigned max; min-index via max of ~n).
//     Two-barrier r7 skeleton restored; owner rescan eliminated (cached wn).

typedef float v2f __attribute__((ext_vector_type(2)));

#define BATCH 8
#define NPTS  8192
#define MSEL  4096
#define NFEAT 256
#define BLOCK 1024
#define NWAVE (BLOCK / 64)

// fp64 square, opaque to the compiler so no v_fma_f64 contraction can merge
// the following adds (numpy float64 does separate mul / add / add).
__device__ __forceinline__ double sqd(double x) {
    double r;
    asm("v_mul_f64 %0, %1, %1" : "=v"(r) : "v"(x));
    return r;
}

// Exact 64-lane u32 max via fused DPP max ops (6 dependent instructions),
// result returned wave-uniform in an SGPR via readlane of lane 63.
// bound_ctrl:0 => out-of-range DPP sources read 0 (identity for unsigned max).
// Requires full exec / uniform control flow at the call site.
// s_nop 1 between steps covers the VALU-write -> DPP-read hazard (2 states).
__device__ __forceinline__ unsigned wave_umax_rl(unsigned v) {
    unsigned s;
    asm volatile(
        "s_nop 1\n\t"
        "v_max_u32_dpp %1, %1, %1 row_shr:1  row_mask:0xf bank_mask:0xf bound_ctrl:0\n\t"
        "s_nop 1\n\t"
        "v_max_u32_dpp %1, %1, %1 row_shr:2  row_mask:0xf bank_mask:0xf bound_ctrl:0\n\t"
        "s_nop 1\n\t"
        "v_max_u32_dpp %1, %1, %1 row_shr:4  row_mask:0xf bank_mask:0xf bound_ctrl:0\n\t"
        "s_nop 1\n\t"
        "v_max_u32_dpp %1, %1, %1 row_shr:8  row_mask:0xf bank_mask:0xf bound_ctrl:0\n\t"
        "s_nop 1\n\t"
        "v_max_u32_dpp %1, %1, %1 row_bcast:15 row_mask:0xf bank_mask:0xf bound_ctrl:0\n\t"
        "s_nop 1\n\t"
        "v_max_u32_dpp %1, %1, %1 row_bcast:31 row_mask:0xf bank_mask:0xf bound_ctrl:0\n\t"
        "s_nop 1\n\t"
        "v_readlane_b32 %0, %1, 63"
        : "=s"(s), "+v"(v));
    return s;
}

__launch_bounds__(BLOCK, 1)
__global__ void fps_kernel(const float* __restrict__ pts,   // [B, N, 3]
                           float* __restrict__ dp,          // [B, M, 3]
                           int* __restrict__ idx_out)       // [B, M]
{
    __shared__ float s_pts[NPTS * 3];          // 96 KB fp32 copy (winner broadcast)
    __shared__ unsigned long long s_bmax[2];   // block max, double bits (nonneg)
    __shared__ int s_widx[2];                  // winner index via atomicMin

    const int b    = blockIdx.x;
    const int tid  = threadIdx.x;
    const int lane = tid & 63;
    const float* p = pts + (size_t)b * NPTS * 3;

    for (int i = tid; i < NPTS * 3; i += BLOCK) s_pts[i] = p[i];
    if (tid == 0) {
        s_bmax[0] = 0ull;        s_bmax[1] = 0ull;
        s_widx[0] = 0x7fffffff;  s_widx[1] = 0x7fffffff;
    }

    // Coords as float2 pairs (slots 2P, 2P+1) -> packed-fp32 screen.
    // mind (fp64 exact) + mfm (pre-margined fp32 screen threshold) per slot.
#define DECLP(P, J0, J1) \
    v2f pxp##P = { p[(tid + J0 * 1024) * 3 + 0], p[(tid + J1 * 1024) * 3 + 0] }; \
    v2f pyp##P = { p[(tid + J0 * 1024) * 3 + 1], p[(tid + J1 * 1024) * 3 + 1] }; \
    v2f pzp##P = { p[(tid + J0 * 1024) * 3 + 2], p[(tid + J1 * 1024) * 3 + 2] };
    DECLP(0, 0, 1) DECLP(1, 2, 3) DECLP(2, 4, 5) DECLP(3, 6, 7)
#undef DECLP
    double mind0 = 1e10, mind1 = 1e10, mind2 = 1e10, mind3 = 1e10;
    double mind4 = 1e10, mind5 = 1e10, mind6 = 1e10, mind7 = 1e10;
    float  mfm0 = 1.0001e10f, mfm1 = 1.0001e10f, mfm2 = 1.0001e10f, mfm3 = 1.0001e10f;
    float  mfm4 = 1.0001e10f, mfm5 = 1.0001e10f, mfm6 = 1.0001e10f, mfm7 = 1.0001e10f;

    // Selection 0 is point 0 (deterministic start).
    float cx = p[0], cy = p[1], cz = p[2];
    if (tid == 0) {
        dp[(size_t)b * MSEL * 3 + 0] = cx;
        dp[(size_t)b * MSEL * 3 + 1] = cy;
        dp[(size_t)b * MSEL * 3 + 2] = cz;
        idx_out[b * MSEL + 0] = 0;
    }

    double   tbv   = 0.0;          // cached thread-local max of mind0..7
    bool     dirty = true;         // lane updated since last wave reduce
    unsigned whi = 0u, wlo = 0u;   // cached wave max (double bits), SGPR
    unsigned wn  = 0x7fffffffu;    // cached wave min-index-at-max, SGPR

    __syncthreads();   // s_pts + slot inits visible

    for (int k = 1; k < MSEL; ++k) {
        const v2f cx2 = {cx, cx}, cy2 = {cy, cy}, cz2 = {cz, cz};

        // --- packed fp32 screen; exact fp64 update only on trigger ---
#define EX64(PX, PY, PZ, J) { \
        const double ddx = (double)(PX) - (double)cx; \
        const double ddy = (double)(PY) - (double)cy; \
        const double ddz = (double)(PZ) - (double)cz; \
        const double dd  = (sqd(ddx) + sqd(ddy)) + sqd(ddz); \
        if (dd < mind##J) { mind##J = dd; mfm##J = (float)dd * 1.0001f; dirty = true; } }
#define UPDP(P, J0, J1) { \
        const v2f dx = pxp##P - cx2, dy = pyp##P - cy2, dz = pzp##P - cz2; \
        const v2f d  = dx * dx + dy * dy + dz * dz; \
        if (d.x < mfm##J0) EX64(pxp##P.x, pyp##P.x, pzp##P.x, J0) \
        if (d.y < mfm##J1) EX64(pxp##P.y, pyp##P.y, pzp##P.y, J1) }
        UPDP(0, 0, 1) UPDP(1, 2, 3) UPDP(2, 4, 5) UPDP(3, 6, 7)
#undef UPDP
#undef EX64

        // --- wave reduce only if some lane in this wave updated ---
        if (__any(dirty)) {
            const double a0 = fmax(mind0, mind1), a1 = fmax(mind2, mind3);
            const double a2 = fmax(mind4, mind5), a3 = fmax(mind6, mind7);
            tbv = fmax(fmax(a0, a1), fmax(a2, a3));
            dirty = false;

            const unsigned long long tb = (unsigned long long)__double_as_longlong(tbv);
            const unsigned thi = (unsigned)(tb >> 32);
            const unsigned tlo = (unsigned)tb;
            whi = wave_umax_rl(thi);
            wlo = wave_umax_rl(thi == whi ? tlo : 0u);

            // per-wave min index among owners (numpy tie-break: global idx =
            // slot*1024 + tid; scan high slot -> low so smallest wins last).
            int n = 0x7fffffff;
            if (thi == whi && tlo == wlo) {
                if (mind7 == tbv) n = tid + 7 * 1024;
                if (mind6 == tbv) n = tid + 6 * 1024;
                if (mind5 == tbv) n = tid + 5 * 1024;
                if (mind4 == tbv) n = tid + 4 * 1024;
                if (mind3 == tbv) n = tid + 3 * 1024;
                if (mind2 == tbv) n = tid + 2 * 1024;
                if (mind1 == tbv) n = tid + 1 * 1024;
                if (mind0 == tbv) n = tid;
            }
            wn = ~wave_umax_rl(~(unsigned)n);   // min over owners
        }

        const unsigned long long mybits =
            ((unsigned long long)whi << 32) | (unsigned long long)wlo;
        if (lane == 0) atomicMax(&s_bmax[k & 1], mybits);
        __syncthreads();                                   // barrier A

        const unsigned long long bmaxbits = s_bmax[k & 1];
        if (tid == 0) {   // reset NEXT iter's slots (between barriers A and B)
            s_bmax[(k + 1) & 1] = 0ull;
            s_widx[(k + 1) & 1] = 0x7fffffff;
        }

        // --- owner waves publish cached min index (one atomic per wave) ---
        if (lane == 0 && mybits == bmaxbits)
            atomicMin(&s_widx[k & 1], (int)wn);
        __syncthreads();                                   // barrier B

        // --- broadcast winner coords from LDS (same-addr = conflict-free) ---
        const int   widx = s_widx[k & 1];
        const float wx = s_pts[widx * 3 + 0];
        const float wy = s_pts[widx * 3 + 1];
        const float wz = s_pts[widx * 3 + 2];
        if (tid == 0) {
            idx_out[b * MSEL + k] = widx;
            float* o = dp + ((size_t)b * MSEL + k) * 3;
            o[0] = wx; o[1] = wy; o[2] = wz;
        }
        cx = wx; cy = wy; cz = wz;
    }
}

// One wave per selected row; lane i moves one float4 (64 * 16B = 1024B = full row).
__global__ void gather_kernel(const float* __restrict__ feats,  // [B, N, C]
                              const int* __restrict__ idx,      // [B, M]
                              float* __restrict__ df)           // [B, M, C]
{
    const int row  = blockIdx.x * 4 + (threadIdx.x >> 6);  // [0, B*M)
    const int lane = threadIdx.x & 63;
    const int b    = row >> 12;         // MSEL = 4096 rows per batch
    const int src  = idx[row];
    const float4* s = (const float4*)(feats + ((size_t)b * NPTS + src) * NFEAT);
    float4*       d = (float4*)(df + (size_t)row * NFEAT);
    d[lane] = s[lane];
}

extern "C" void kernel_launch(void* const* d_in, const int* in_sizes, int n_in,
                              void* d_out, int out_size, void* d_ws, size_t ws_size,
                              hipStream_t stream)
{
    const float* points   = (const float*)d_in[0];   // [8, 8192, 3]
    const float* features = (const float*)d_in[1];   // [8, 8192, 256]
    float* out = (float*)d_out;
    float* dp  = out;                                // [8, 4096, 3]
    float* df  = out + (size_t)BATCH * MSEL * 3;     // [8, 4096, 256]
    int*   idx_ws = (int*)d_ws;                      // [8, 4096] = 128 KB scratch

    fps_kernel<<<BATCH, BLOCK, 0, stream>>>(points, dp, idx_ws);
    gather_kernel<<<(BATCH * MSEL) / 4, 256, 0, stream>>>(features, idx_ws, df);
}